// Round 11
// baseline (669.393 us; speedup 1.0000x reference)
//
#include <hip/hip_runtime.h>
#include <stdint.h>

#define BATCH 8
#define NPTS 8192
#define NGRP 512
#define KNN 32
#define NCH 6

#define FPS_T 256
#define FPS_PPT (NPTS / FPS_T)   // 32 points per thread
#define PAIRS (FPS_PPT / 2)      // 16 packed pairs
#define FPS_NW (FPS_T / 64)      // 4 waves

#define NBLK 248                 // <= 256, 1 block/CU (LDS) => all co-resident
#define KNN_WAVES ((NBLK - BATCH) * FPS_NW)   // 960
#define NCAND 512                // candidate-set capacity (8 per lane of wave 0)
#define DONE_TAG 0xFFFFFFFFu

typedef float f2 __attribute__((ext_vector_type(2)));
typedef float f4 __attribute__((ext_vector_type(4)));

// packed f32 ops (VOP3P): IEEE rn per lane — bit-identical to scalar ops.
// add(x,-c) == sub(x,c) exactly.
__device__ __forceinline__ f2 pk_add(f2 a, f2 b) {
    f2 d;
    asm("v_pk_add_f32 %0, %1, %2" : "=v"(d) : "v"(a), "v"(b));
    return d;
}
__device__ __forceinline__ f2 pk_mul(f2 a, f2 b) {
    f2 d;
    asm("v_pk_mul_f32 %0, %1, %2" : "=v"(d) : "v"(a), "v"(b));
    return d;
}

__device__ __forceinline__ unsigned long long max64(unsigned long long a,
                                                    unsigned long long b) {
    return (a > b) ? a : b;
}

// DPP 64-bit max stage; invalid-source lanes keep own value (max is no-op).
template <int CTRL>
__device__ __forceinline__ unsigned long long dpp_max64(unsigned long long k) {
    int lo = (int)(unsigned)k;
    int hi = (int)(unsigned)(k >> 32);
    int plo = __builtin_amdgcn_update_dpp(lo, lo, CTRL, 0xF, 0xF, false);
    int phi = __builtin_amdgcn_update_dpp(hi, hi, CTRL, 0xF, 0xF, false);
    unsigned long long o =
        ((unsigned long long)(unsigned)phi << 32) | (unsigned)plo;
    return max64(o, k);
}

// directional wave max -> lane 63 (row_shr 1/2/4/8, row_bcast 15/31)
__device__ __forceinline__ unsigned long long wave_max_dir(unsigned long long k) {
    k = dpp_max64<0x111>(k);
    k = dpp_max64<0x112>(k);
    k = dpp_max64<0x114>(k);
    k = dpp_max64<0x118>(k);
    k = dpp_max64<0x142>(k);
    k = dpp_max64<0x143>(k);
    return k;
}

// all-lanes wave max (xor pattern, proven in R4): quad_perm xor1/xor2,
// row_half_mirror, row_mirror, then shfl_xor 16/32.
__device__ __forceinline__ unsigned long long wave_max_all(unsigned long long k) {
    k = dpp_max64<0xB1>(k);
    k = dpp_max64<0x4E>(k);
    k = dpp_max64<0x141>(k);
    k = dpp_max64<0x140>(k);
    unsigned long long o = __shfl_xor(k, 16, 64);
    k = max64(k, o);
    o = __shfl_xor(k, 32, 64);
    k = max64(k, o);
    return k;
}

// --------- kNN key: exact reference einsum numerics ---------
__device__ __forceinline__ unsigned long long knn_key(const float* __restrict__ base,
                                                      int p, float cx, float cy,
                                                      float cz, float cc) {
    float x = base[p * NCH + 0];
    float y = base[p * NCH + 1];
    float z = base[p * NCH + 2];
    float xx = __fadd_rn(__fadd_rn(__fmul_rn(x, x), __fmul_rn(y, y)), __fmul_rn(z, z));
    float dt = fmaf(cz, z, fmaf(cy, y, __fmul_rn(cx, x)));
    float d2 = __fsub_rn(__fadd_rn(cc, xx), __fmul_rn(2.0f, dt));
    unsigned int bits = __float_as_uint(d2);
    unsigned int ord = bits ^ ((unsigned)((int)bits >> 31) | 0x80000000u);
    return ((unsigned long long)ord << 13) | (unsigned)p;
}

// --------- fused producer-consumer kernel ---------
// blocks [0,8): lazy FPS. blocks [8,248): kNN consumers (s_sleep spin).
__global__ __launch_bounds__(FPS_T, 1) void fused_kernel(const float* __restrict__ pts,
                                                         float* __restrict__ out_ctr,
                                                         float* __restrict__ out_nb,
                                                         unsigned int* __restrict__ faridx,
                                                         int fstride) {
    __shared__ float xs[NPTS], ys[NPTS], zs[NPTS];
    __shared__ float ctr_lds[NGRP * 3];
    __shared__ unsigned long long slots[FPS_NW];
    __shared__ f4 candP[NCAND];       // {x, y, z, idx_bits}
    __shared__ float cvA[NCAND];      // candidate running dist
    __shared__ unsigned ctl_gshared;
    __shared__ int ctl_count;

    const int tid = threadIdx.x;

    if (blockIdx.x < BATCH) {
        // ================= lazy FPS role =================
        const int b = blockIdx.x;
        const float* base = pts + (size_t)b * NPTS * NCH;

        f2 x2[PAIRS], y2[PAIRS], z2[PAIRS], dist2[PAIRS];
#pragma unroll
        for (int i = 0; i < PAIRS; ++i) {
            int p0 = tid + (2 * i) * FPS_T;
            int p1 = tid + (2 * i + 1) * FPS_T;
            float xa = base[p0 * NCH + 0], ya = base[p0 * NCH + 1], za = base[p0 * NCH + 2];
            float xb = base[p1 * NCH + 0], yb = base[p1 * NCH + 1], zb = base[p1 * NCH + 2];
            x2[i] = (f2){xa, xb};
            y2[i] = (f2){ya, yb};
            z2[i] = (f2){za, zb};
            dist2[i] = (f2){1e10f, 1e10f};
            xs[p0] = xa; ys[p0] = ya; zs[p0] = za;
            xs[p1] = xb; ys[p1] = yb; zs[p1] = zb;
        }
        __syncthreads();

        const int wid  = tid >> 6;
        const int lane = tid & 63;

        int far = 0, g = 0, lastFold = 0, cnt = 0;
        bool valid = false;          // candidate set not built yet
        float vb = 0.0f;

        while (true) {
            if (wid == 0) {
                // ---- wave-0 cheap loop: no block barrier inside ----
                while (true) {
                    float ccx = xs[far], ccy = ys[far], ccz = zs[far];
                    if (lane == 0) {
                        ctr_lds[g * 3 + 0] = ccx;
                        ctr_lds[g * 3 + 1] = ccy;
                        ctr_lds[g * 3 + 2] = ccz;
                        __hip_atomic_store(&faridx[(b * NGRP + g) * fstride],
                                           (unsigned)far, __ATOMIC_RELAXED,
                                           __HIP_MEMORY_SCOPE_AGENT);
                    }
                    if (g == NGRP - 1) {
                        if (lane == 0) ctl_gshared = DONE_TAG;
                        break;
                    }
                    if (!valid) {
                        if (lane == 0) ctl_gshared = (unsigned)g;
                        break;
                    }
                    // update candidates vs c_g; exact numpy op order
                    unsigned long long wkey = 0;
#pragma unroll
                    for (int s = 0; s < NCAND / 64; ++s) {
                        int i = lane + s * 64;
                        if (i < cnt) {
                            f4 P = candP[i];
                            float pv = cvA[i];
                            float dx = __fsub_rn(P.x, ccx);
                            float dy = __fsub_rn(P.y, ccy);
                            float dz = __fsub_rn(P.z, ccz);
                            float d = __fadd_rn(__fadd_rn(__fmul_rn(dx, dx),
                                                          __fmul_rn(dy, dy)),
                                                __fmul_rn(dz, dz));
                            float nv = fminf(pv, d);
                            cvA[i] = nv;
                            unsigned idx = __float_as_uint(P.w);
                            unsigned long long k =
                                ((unsigned long long)__float_as_uint(nv) << 13) |
                                (unsigned)(8191 - idx);
                            wkey = max64(wkey, k);
                        }
                    }
                    wkey = wave_max_all(wkey);
                    float wv = __uint_as_float((unsigned)(wkey >> 13));
                    if (!(wv > vb)) {        // winner might be outside S -> rebuild
                        if (lane == 0) ctl_gshared = (unsigned)g;
                        break;
                    }
                    far = 8191 - (int)(wkey & 0x1FFFULL);
                    ++g;
                }
            }
            __syncthreads();                      // episode barrier
            unsigned gr = ctl_gshared;
            if (gr == DONE_TAG) break;
            if (tid == 0) ctl_count = 0;

            // ---- catch-up: fold missed centroids [lastFold, gr) (no argmax) ----
            for (int h = lastFold; h < (int)gr; ++h) {
                float ccx = ctr_lds[h * 3 + 0];
                float ccy = ctr_lds[h * 3 + 1];
                float ccz = ctr_lds[h * 3 + 2];
                f2 ncx = (f2){-ccx, -ccx};
                f2 ncy = (f2){-ccy, -ccy};
                f2 ncz = (f2){-ccz, -ccz};
#pragma unroll
                for (int i = 0; i < PAIRS; ++i) {
                    f2 dx = pk_add(x2[i], ncx);
                    f2 dy = pk_add(y2[i], ncy);
                    f2 dz = pk_add(z2[i], ncz);
                    f2 sx = pk_mul(dx, dx);
                    f2 sy = pk_mul(dy, dy);
                    f2 t  = pk_add(sx, sy);
                    f2 sz = pk_mul(dz, dz);
                    f2 d  = pk_add(t, sz);
                    dist2[i].x = fminf(dist2[i].x, d.x);
                    dist2[i].y = fminf(dist2[i].y, d.y);
                }
            }

            // ---- fold c_gr WITH argmax (normal path) ----
            {
                float ccx = ctr_lds[gr * 3 + 0];
                float ccy = ctr_lds[gr * 3 + 1];
                float ccz = ctr_lds[gr * 3 + 2];
                f2 ncx = (f2){-ccx, -ccx};
                f2 ncy = (f2){-ccy, -ccy};
                f2 ncz = (f2){-ccz, -ccz};
                float bestv = -1.0f;
                int bestj = 0;
#pragma unroll
                for (int i = 0; i < PAIRS; ++i) {
                    f2 dx = pk_add(x2[i], ncx);
                    f2 dy = pk_add(y2[i], ncy);
                    f2 dz = pk_add(z2[i], ncz);
                    f2 sx = pk_mul(dx, dx);
                    f2 sy = pk_mul(dy, dy);
                    f2 t  = pk_add(sx, sy);
                    f2 sz = pk_mul(dz, dz);
                    f2 d  = pk_add(t, sz);
                    float nd0 = fminf(dist2[i].x, d.x);
                    float nd1 = fminf(dist2[i].y, d.y);
                    dist2[i].x = nd0;
                    dist2[i].y = nd1;
                    if (nd0 > bestv) { bestv = nd0; bestj = 2 * i; }
                    if (nd1 > bestv) { bestv = nd1; bestj = 2 * i + 1; }
                }
                int bestp = tid + bestj * FPS_T;
                unsigned long long key =
                    ((unsigned long long)__float_as_uint(bestv) << 13) |
                    (unsigned)(8191 - bestp);
                key = wave_max_dir(key);
                if (lane == 63) slots[wid] = key;
            }
            __syncthreads();                      // slots + count reset visible

            unsigned long long m01 = max64(slots[0], slots[1]);
            unsigned long long m23 = max64(slots[2], slots[3]);
            unsigned long long best = max64(m01, m23);
            far = 8191 - (int)(best & 0x1FFFULL);
            float M = __uint_as_float((unsigned)(best >> 13));

            // ---- compact candidate set S = {dist >= vb}, retry once on overflow ----
            float vbTry = __fmul_rn(0.80f, M);
            for (int attempt = 0; attempt < 2; ++attempt) {
#pragma unroll
                for (int i = 0; i < PAIRS; ++i) {
                    float v0 = dist2[i].x, v1 = dist2[i].y;
                    if (v0 >= vbTry) {
                        int pos = atomicAdd(&ctl_count, 1);
                        if (pos < NCAND) {
                            candP[pos] = (f4){x2[i].x, y2[i].x, z2[i].x,
                                              __uint_as_float((unsigned)(tid + (2 * i) * FPS_T))};
                            cvA[pos] = v0;
                        }
                    }
                    if (v1 >= vbTry) {
                        int pos = atomicAdd(&ctl_count, 1);
                        if (pos < NCAND) {
                            candP[pos] = (f4){x2[i].y, y2[i].y, z2[i].y,
                                              __uint_as_float((unsigned)(tid + (2 * i + 1) * FPS_T))};
                            cvA[pos] = v1;
                        }
                    }
                }
                __syncthreads();
                int c = ctl_count;
                if (c <= NCAND) { valid = true; cnt = c; vb = vbTry; break; }
                if (attempt == 0) {
                    if (tid == 0) ctl_count = 0;
                    vbTry = __fmul_rn(0.95f, M);
                    __syncthreads();
                } else {
                    valid = false;   // fall back to rebuild-every-iteration
                }
            }

            g = (int)gr + 1;
            lastFold = (int)gr + 1;
        }

        // flush centroids to global, coalesced
        float* ctr = out_ctr + (size_t)b * NGRP * 3;
        for (int i = tid; i < NGRP * 3; i += FPS_T) ctr[i] = ctr_lds[i];

    } else {
        // ================= kNN role (unchanged from R6) =================
        const int wid  = tid >> 6;
        const int lane = tid & 63;
        const int W = (blockIdx.x - BATCH) * FPS_NW + wid;   // [0, 960)

        for (int e = W; e < BATCH * NGRP; e += KNN_WAVES) {
            const int g  = e >> 3;
            const int b  = e & 7;
            const int bg = b * NGRP + g;
            const float* base = pts + (size_t)b * NPTS * NCH;

            unsigned fidx;
            if (lane == 0) {
                while ((fidx = __hip_atomic_load(&faridx[bg * fstride],
                                                 __ATOMIC_RELAXED,
                                                 __HIP_MEMORY_SCOPE_AGENT)) == 0xFFFFFFFFu)
                    __builtin_amdgcn_s_sleep(8);
            }
            fidx = (unsigned)__shfl((int)fidx, 0, 64);

            const float cx = base[fidx * NCH + 0];
            const float cy = base[fidx * NCH + 1];
            const float cz = base[fidx * NCH + 2];
            const float cc = __fadd_rn(__fadd_rn(__fmul_rn(cx, cx), __fmul_rn(cy, cy)),
                                       __fmul_rn(cz, cz));

            unsigned long long R = knn_key(base, lane, cx, cy, cz, cc);
#pragma unroll
            for (int k = 2; k <= 64; k <<= 1) {
#pragma unroll
                for (int j = k >> 1; j > 0; j >>= 1) {
                    unsigned long long o = __shfl_xor(R, j, 64);
                    bool takeMin = (((lane & k) == 0) == ((lane & j) == 0));
                    unsigned long long mn = (o < R) ? o : R;
                    unsigned long long mx = (o < R) ? R : o;
                    R = takeMin ? mn : mx;
                }
            }
            unsigned long long R31 = __shfl(R, 31, 64);

            for (int c = 1; c < NPTS / 64; ++c) {
                unsigned long long key = knn_key(base, c * 64 + lane, cx, cy, cz, cc);
                unsigned long long qual = __ballot(key < R31);
                while (qual) {
                    int src = __ffsll(qual) - 1;
                    qual &= qual - 1;
                    unsigned long long bk = __shfl(key, src, 64);
                    int rank = __popcll(__ballot(R < bk));
                    unsigned long long Rp = __shfl_up(R, 1, 64);
                    R = (lane == rank) ? bk : ((lane > rank) ? Rp : R);
                    R31 = __shfl(R, 31, 64);
                }
            }

            if (lane < KNN) {
                int idx = (int)(R & 8191ULL);
                const float* s = base + (size_t)idx * NCH;
                float* d = out_nb + ((size_t)bg * KNN + lane) * NCH;
                d[0] = s[0] - cx;
                d[1] = s[1] - cy;
                d[2] = s[2] - cz;
                d[3] = s[3];
                d[4] = s[4];
                d[5] = s[5];
            }
        }
    }
}

extern "C" void kernel_launch(void* const* d_in, const int* in_sizes, int n_in,
                              void* d_out, int out_size, void* d_ws, size_t ws_size,
                              hipStream_t stream) {
    const float* pts = (const float*)d_in[0];
    float* out = (float*)d_out;
    float* out_nb  = out;                                    // (8,512,32,6)
    float* out_ctr = out + (size_t)BATCH * NGRP * KNN * NCH; // (8,512,3)

    const size_t nctr = (size_t)BATCH * NGRP;
    int fstride = (ws_size >= nctr * 16 * sizeof(unsigned)) ? 16 : 1;
    unsigned int* faridx = (unsigned int*)d_ws;

    hipMemsetAsync(d_ws, 0xFF, nctr * (size_t)fstride * sizeof(unsigned), stream);
    hipLaunchKernelGGL(fused_kernel, dim3(NBLK), dim3(FPS_T), 0, stream,
                       pts, out_ctr, out_nb, faridx, fstride);
}

// Round 12
// 549.535 us; speedup vs baseline: 1.2181x; 1.2181x over previous
//
#include <hip/hip_runtime.h>
#include <stdint.h>

#define BATCH 8
#define NPTS 8192
#define NGRP 512
#define KNN 32
#define NCH 6

#define FPS_T 256
#define FPS_PPT (NPTS / FPS_T)   // 32 points per thread
#define PAIRS (FPS_PPT / 2)      // 16 packed pairs
#define FPS_NW (FPS_T / 64)      // 4 waves

#define NBLK 248                 // <= 256, 1 block/CU (LDS) => all co-resident
#define KNN_WAVES ((NBLK - BATCH) * FPS_NW)   // 960

typedef float f2 __attribute__((ext_vector_type(2)));

// packed f32 ops (VOP3P): 2 points per instruction, IEEE rn per lane —
// bit-identical to scalar __fadd_rn/__fmul_rn. add(x,-c) == sub(x,c) exactly.
__device__ __forceinline__ f2 pk_add(f2 a, f2 b) {
    f2 d;
    asm("v_pk_add_f32 %0, %1, %2" : "=v"(d) : "v"(a), "v"(b));
    return d;
}
__device__ __forceinline__ f2 pk_mul(f2 a, f2 b) {
    f2 d;
    asm("v_pk_mul_f32 %0, %1, %2" : "=v"(d) : "v"(a), "v"(b));
    return d;
}

__device__ __forceinline__ unsigned long long max64(unsigned long long a,
                                                    unsigned long long b) {
    return (a > b) ? a : b;
}

// 64-bit max butterfly stage via DPP only (no LDS-pipe shuffles).
// Directional reduce: row_shr 1/2/4/8 then row_bcast 15/31 -> lane 63 of the
// wave holds the max. Invalid lanes keep old (= own value) -> max is a no-op.
template <int CTRL>
__device__ __forceinline__ unsigned long long dpp_max64(unsigned long long k) {
    int lo = (int)(unsigned)k;
    int hi = (int)(unsigned)(k >> 32);
    int plo = __builtin_amdgcn_update_dpp(lo, lo, CTRL, 0xF, 0xF, false);
    int phi = __builtin_amdgcn_update_dpp(hi, hi, CTRL, 0xF, 0xF, false);
    unsigned long long o =
        ((unsigned long long)(unsigned)phi << 32) | (unsigned)plo;
    return max64(o, k);
}

__device__ __forceinline__ unsigned long long wave_max_dir(unsigned long long k) {
    k = dpp_max64<0x111>(k);   // row_shr:1
    k = dpp_max64<0x112>(k);   // row_shr:2
    k = dpp_max64<0x114>(k);   // row_shr:4
    k = dpp_max64<0x118>(k);   // row_shr:8
    k = dpp_max64<0x142>(k);   // row_bcast:15
    k = dpp_max64<0x143>(k);   // row_bcast:31
    return k;
}

// --------- kNN key: exact reference einsum numerics ---------
// xx: separate numpy ufuncs (x**2 then sum) -> sequential rounded ops.
// dot: einsum inner loop FMA-contracted ascending: fma(cz,z, fma(cy,y, rn(cx*x)))
__device__ __forceinline__ unsigned long long knn_key(const float* __restrict__ base,
                                                      int p, float cx, float cy,
                                                      float cz, float cc) {
    float x = base[p * NCH + 0];
    float y = base[p * NCH + 1];
    float z = base[p * NCH + 2];
    float xx = __fadd_rn(__fadd_rn(__fmul_rn(x, x), __fmul_rn(y, y)), __fmul_rn(z, z));
    float dt = fmaf(cz, z, fmaf(cy, y, __fmul_rn(cx, x)));
    float d2 = __fsub_rn(__fadd_rn(cc, xx), __fmul_rn(2.0f, dt));
    unsigned int bits = __float_as_uint(d2);
    unsigned int ord = bits ^ ((unsigned)((int)bits >> 31) | 0x80000000u);
    return ((unsigned long long)ord << 13) | (unsigned)p;
}

// --------- fused producer-consumer kernel ---------
// blocks [0,8): FPS, one per batch. blocks [8,248): kNN consumers (s_sleep
// spin — hot spinning at scale trips the power governor, R7/R8 evidence).
// min-waves-per-EU = 1: LDS already pins 1 block/CU, so let the register
// allocator use the full file — the FPS update needs ~230 VGPRs to run all
// 16 pair-chains in parallel instead of serializing on 4 scratch regs.
__global__ __launch_bounds__(FPS_T, 1) void fused_kernel(const float* __restrict__ pts,
                                                         float* __restrict__ out_ctr,
                                                         float* __restrict__ out_nb,
                                                         unsigned int* __restrict__ faridx,
                                                         int fstride) {
    __shared__ float xs[NPTS], ys[NPTS], zs[NPTS];
    __shared__ float ctr_lds[NGRP * 3];
    __shared__ unsigned long long slots[2][FPS_NW];

    const int tid = threadIdx.x;

    if (blockIdx.x < BATCH) {
        // ================= FPS role =================
        const int b = blockIdx.x;
        const float* base = pts + (size_t)b * NPTS * NCH;

        f2 x2[PAIRS], y2[PAIRS], z2[PAIRS], dist2[PAIRS];
        unsigned inv[FPS_PPT];   // 8191 - p  (loop-invariant key low word)
#pragma unroll
        for (int i = 0; i < PAIRS; ++i) {
            int p0 = tid + (2 * i) * FPS_T;
            int p1 = tid + (2 * i + 1) * FPS_T;
            float xa = base[p0 * NCH + 0], ya = base[p0 * NCH + 1], za = base[p0 * NCH + 2];
            float xb = base[p1 * NCH + 0], yb = base[p1 * NCH + 1], zb = base[p1 * NCH + 2];
            x2[i] = (f2){xa, xb};
            y2[i] = (f2){ya, yb};
            z2[i] = (f2){za, zb};
            dist2[i] = (f2){1e10f, 1e10f};
            inv[2 * i]     = (unsigned)(8191 - p0);
            inv[2 * i + 1] = (unsigned)(8191 - p1);
            xs[p0] = xa; ys[p0] = ya; zs[p0] = za;
            xs[p1] = xb; ys[p1] = yb; zs[p1] = zb;
        }
        __syncthreads();

        int far = 0;
        const int wid  = tid >> 6;
        const int lane = tid & 63;

        for (int g = 0; g < NGRP; ++g) {
            // centroid for group g = point `far` (known at top of iter g)
            float cx = xs[far], cy = ys[far], cz = zs[far];
            if (tid == 0) {
                ctr_lds[g * 3 + 0] = cx;
                ctr_lds[g * 3 + 1] = cy;
                ctr_lds[g * 3 + 2] = cz;
                // publish index -> unblocks this center's kNN wave. relaxed is
                // enough: the index alone determines the centroid (pts is
                // read-only device-wide).
                __hip_atomic_store(&faridx[(b * NGRP + g) * fstride], (unsigned)far,
                                   __ATOMIC_RELAXED, __HIP_MEMORY_SCOPE_AGENT);
            }
            if (g == NGRP - 1) break;   // no further update needed

            f2 ncx = (f2){-cx, -cx};
            f2 ncy = (f2){-cy, -cy};
            f2 ncz = (f2){-cz, -cz};

            // ---- phase 1: independent distance chains (full ILP) ----
            // numpy semantics: (dx^2 + dy^2) + dz^2, each op rn, no FMA.
            f2 nd2[PAIRS];
#pragma unroll
            for (int i = 0; i < PAIRS; ++i) {
                f2 dx = pk_add(x2[i], ncx);
                f2 dy = pk_add(y2[i], ncy);
                f2 dz = pk_add(z2[i], ncz);
                f2 sx = pk_mul(dx, dx);
                f2 sy = pk_mul(dy, dy);
                f2 t  = pk_add(sx, sy);
                f2 sz = pk_mul(dz, dz);
                f2 d  = pk_add(t, sz);
                nd2[i].x = fminf(dist2[i].x, d.x);
                nd2[i].y = fminf(dist2[i].y, d.y);
                dist2[i] = nd2[i];
            }

            // ---- phase 2: explicit 64-bit key max tree (depth 5, parallel).
            // key = (float bits of dist << 32) | (8191 - p): dist >= 0 so the
            // value word is monotone; ties -> larger low word = smaller index
            // = numpy first-occurrence argmax.
            unsigned long long km[PAIRS];
#pragma unroll
            for (int i = 0; i < PAIRS; ++i) {
                unsigned long long k0 =
                    ((unsigned long long)__float_as_uint(nd2[i].x) << 32) | inv[2 * i];
                unsigned long long k1 =
                    ((unsigned long long)__float_as_uint(nd2[i].y) << 32) | inv[2 * i + 1];
                km[i] = max64(k0, k1);
            }
#pragma unroll
            for (int s = PAIRS / 2; s >= 1; s >>= 1) {
#pragma unroll
                for (int i = 0; i < s; ++i) km[i] = max64(km[i], km[i + s]);
            }

            // wave max, all-DPP (VALU pipe only): lane 63 gets wave max
            unsigned long long key = wave_max_dir(km[0]);
            if (lane == 63) slots[g & 1][wid] = key;
            __syncthreads();

            const unsigned long long* sp = slots[g & 1];
            unsigned long long best = max64(max64(sp[0], sp[1]),
                                            max64(sp[2], sp[3]));
            far = 8191 - (int)(best & 0xFFFFFFFFULL);
        }

        __syncthreads();   // ctr_lds[last] written by tid 0
        // flush centroids to global, coalesced
        float* ctr = out_ctr + (size_t)b * NGRP * 3;
        for (int i = tid; i < NGRP * 3; i += FPS_T) ctr[i] = ctr_lds[i];

    } else {
        // ================= kNN role (R6-proven, s_sleep spin) =================
        const int wid  = tid >> 6;
        const int lane = tid & 63;
        const int W = (blockIdx.x - BATCH) * FPS_NW + wid;   // [0, 960)

        // enumerate centers in ascending-g order (availability order):
        // e = g*8 + b  ->  wave W handles e = W, W+960, ...
        for (int e = W; e < BATCH * NGRP; e += KNN_WAVES) {
            const int g  = e >> 3;
            const int b  = e & 7;
            const int bg = b * NGRP + g;
            const float* base = pts + (size_t)b * NPTS * NCH;

            // spin until fps publishes this center's index
            unsigned fidx;
            if (lane == 0) {
                while ((fidx = __hip_atomic_load(&faridx[bg * fstride],
                                                 __ATOMIC_RELAXED,
                                                 __HIP_MEMORY_SCOPE_AGENT)) == 0xFFFFFFFFu)
                    __builtin_amdgcn_s_sleep(8);
            }
            fidx = (unsigned)__shfl((int)fidx, 0, 64);

            const float cx = base[fidx * NCH + 0];
            const float cy = base[fidx * NCH + 1];
            const float cz = base[fidx * NCH + 2];
            const float cc = __fadd_rn(__fadd_rn(__fmul_rn(cx, cx), __fmul_rn(cy, cy)),
                                       __fmul_rn(cz, cz));

            // chunk 0 -> bitonic sort 64 keys across the wave
            unsigned long long R = knn_key(base, lane, cx, cy, cz, cc);
#pragma unroll
            for (int k = 2; k <= 64; k <<= 1) {
#pragma unroll
                for (int j = k >> 1; j > 0; j >>= 1) {
                    unsigned long long o = __shfl_xor(R, j, 64);
                    bool takeMin = (((lane & k) == 0) == ((lane & j) == 0));
                    unsigned long long mn = (o < R) ? o : R;
                    unsigned long long mx = (o < R) ? R : o;
                    R = takeMin ? mn : mx;
                }
            }
            unsigned long long R31 = __shfl(R, 31, 64);

            // stream remaining chunks; insert candidates beating current 32nd
            for (int c = 1; c < NPTS / 64; ++c) {
                unsigned long long key = knn_key(base, c * 64 + lane, cx, cy, cz, cc);
                unsigned long long qual = __ballot(key < R31);
                while (qual) {
                    int src = __ffsll(qual) - 1;
                    qual &= qual - 1;
                    unsigned long long bk = __shfl(key, src, 64);
                    int rank = __popcll(__ballot(R < bk));
                    unsigned long long Rp = __shfl_up(R, 1, 64);
                    R = (lane == rank) ? bk : ((lane > rank) ? Rp : R);
                    R31 = __shfl(R, 31, 64);
                }
            }

            // gather: lanes 0..31 hold the sorted top-32
            if (lane < KNN) {
                int idx = (int)(R & 8191ULL);
                const float* s = base + (size_t)idx * NCH;
                float* d = out_nb + ((size_t)bg * KNN + lane) * NCH;
                d[0] = s[0] - cx;
                d[1] = s[1] - cy;
                d[2] = s[2] - cz;
                d[3] = s[3];
                d[4] = s[4];
                d[5] = s[5];
            }
        }
    }
}

extern "C" void kernel_launch(void* const* d_in, const int* in_sizes, int n_in,
                              void* d_out, int out_size, void* d_ws, size_t ws_size,
                              hipStream_t stream) {
    const float* pts = (const float*)d_in[0];
    float* out = (float*)d_out;
    float* out_nb  = out;                                    // (8,512,32,6)
    float* out_ctr = out + (size_t)BATCH * NGRP * KNN * NCH; // (8,512,3)

    // per-center published index; 64B stride => 1 writer + 1 reader per line
    const size_t nctr = (size_t)BATCH * NGRP;
    int fstride = (ws_size >= nctr * 16 * sizeof(unsigned)) ? 16 : 1;
    unsigned int* faridx = (unsigned int*)d_ws;

    hipMemsetAsync(d_ws, 0xFF, nctr * (size_t)fstride * sizeof(unsigned), stream);
    hipLaunchKernelGGL(fused_kernel, dim3(NBLK), dim3(FPS_T), 0, stream,
                       pts, out_ctr, out_nb, faridx, fstride);
}